// Round 13
// baseline (609.246 us; speedup 1.0000x reference)
//
#include <hip/hip_runtime.h>
#include <hip/hip_bf16.h>
#include <hip/hip_fp16.h>
#include <math.h>

#define NNODES 50000

typedef __attribute__((ext_vector_type(8))) short short8v;
typedef __attribute__((ext_vector_type(4))) float f32x4;
typedef unsigned short ushort_t;
typedef unsigned int uint_t;

// ---------------- bf16 / fp16 helpers ----------------
__device__ inline ushort_t f2bf_bits(float v) {
    union { __hip_bfloat16 b; ushort_t u; } c;
    c.b = __float2bfloat16(v);
    return c.u;
}
__device__ inline float bfbits2f(ushort_t u) {
    union { __hip_bfloat16 b; ushort_t u; } c;
    c.u = u;
    return __bfloat162float(c.b);
}
__device__ inline ushort_t f2h_bits(float v) {
    union { __half h; ushort_t u; } c;
    c.h = __float2half(v);
    return c.u;
}
__device__ inline void cvt2(uint_t u, float& a, float& b) {
    union { uint_t u; __half2 h; } c; c.u = u;
    a = __low2float(c.h); b = __high2float(c.h);
}
// monotone float<->uint mapping (for atomicMax on floats incl. negatives)
__device__ inline uint_t fmap(float f) {
    uint_t b = __float_as_uint(f);
    return (b & 0x80000000u) ? ~b : (b | 0x80000000u);
}
__device__ inline float funmap(uint_t u) {
    return __uint_as_float((u & 0x80000000u) ? (u & 0x7FFFFFFFu) : ~u);
}

// split fp32 -> (hi, lo) bf16 pair, vectorized x4
__global__ __launch_bounds__(256)
void split_kernel(const float4* __restrict__ in, ushort4* __restrict__ hi,
                  ushort4* __restrict__ lo, int n4) {
    int i = blockIdx.x * blockDim.x + threadIdx.x;
    if (i >= n4) return;
    float4 v = in[i];
    ushort4 h, l;
    h.x = f2bf_bits(v.x); l.x = f2bf_bits(v.x - bfbits2f(h.x));
    h.y = f2bf_bits(v.y); l.y = f2bf_bits(v.y - bfbits2f(h.y));
    h.z = f2bf_bits(v.z); l.z = f2bf_bits(v.z - bfbits2f(h.z));
    h.w = f2bf_bits(v.w); l.w = f2bf_bits(v.w - bfbits2f(h.w));
    hi[i] = h; lo[i] = l;
}

// all three weight transposes/splits in one launch
__global__ __launch_bounds__(256)
void wprep_all(const float* __restrict__ W1, const float* __restrict__ W2,
               const float* __restrict__ W3,
               ushort_t* __restrict__ w1h, ushort_t* __restrict__ w1l,
               ushort_t* __restrict__ w2h, ushort_t* __restrict__ w2l,
               ushort_t* __restrict__ w3h, ushort_t* __restrict__ w3l) {
    int idx = blockIdx.x * blockDim.x + threadIdx.x;
    const float* W; ushort_t* hT; ushort_t* lT; int K, N;
    if (idx < 128 * 256) { W = W1; hT = w1h; lT = w1l; K = 128; N = 256; }
    else if (idx < 128 * 256 + 256 * 256) {
        idx -= 128 * 256; W = W2; hT = w2h; lT = w2l; K = 256; N = 256;
    } else {
        idx -= 128 * 256 + 256 * 256;
        if (idx >= 256 * 384) return;
        W = W3; hT = w3h; lT = w3l; K = 256; N = 384;
    }
    int k = idx / N, n = idx - k * N;
    float v = W[idx];
    ushort_t hb = f2bf_bits(v);
    hT[(size_t)n * K + k] = hb;
    lT[(size_t)n * K + k] = f2bf_bits(v - bfbits2f(hb));
}

// ============ fused split-bf16 3-pass MFMA GEMM + pack + score ==============
// C = A[M][K] * B[K][N] (B stored transposed [N][K], hi/lo bf16).
// BM=64, BN=HB*64 (HB heads per block), BK=32; 4 waves (2x2), wave tile
// 32 x (HB*32). HB=H (NC=1) for layers 2/3 removes all A-panel refetch.
// LDS staging k-chunk-major: conflict-free ds_read_b128 fragments.
// Epilogue: acc -> LDS fp16 (XOR-swizzled) -> HB/2 head-pair planes
// h16[p][n][c][2], fused per-head s_src/s_dst dot-reduce, per-head global max.
template<int H, int HB>
__global__ __launch_bounds__(256)
void gemm_fused(const ushort_t* __restrict__ Ahi, const ushort_t* __restrict__ Alo,
                const ushort_t* __restrict__ Bhi, const ushort_t* __restrict__ Blo,
                ushort_t* __restrict__ h16, float* __restrict__ ssrc,
                float* __restrict__ sdst, uint_t* __restrict__ gmaxu,
                const float* __restrict__ a_src, const float* __restrict__ a_dst,
                int M, int K) {
    constexpr int BCH = HB * 1024;          // B LDS k-chunk stride (HB*64 rows x 16B)
    constexpr int SMEMB = 8192 + 2 * HB * 4096;   // A(8KB) + B hi/lo
    constexpr int HW = HB / 2;              // heads per wave
    __shared__ char smem[SMEMB];            // staging / epilogue h2 union
    __shared__ float sSs[64][HB], sDs[64][HB];
    __shared__ uint_t gblk[8];

    const int tid = threadIdx.x;
    const int lane = tid & 63;
    const int wid = tid >> 6;
    const int wm = wid >> 1, wn = wid & 1;
    const int bm = blockIdx.y * 64;
    const int bn = blockIdx.x * (HB * 64);
    const int r15 = lane & 15;
    const int g4 = lane >> 4;

    if (tid < HB) gblk[tid] = 0;

    char* As_hi = smem;                     // 4 chunks x 64 rows x 16B = 4KB
    char* As_lo = smem + 4096;
    char* Bs_hi = smem + 8192;              // 4 chunks x HB*64 rows x 16B
    char* Bs_lo = smem + 8192 + HB * 4096;

    const int srow = tid >> 2;              // 0..63
    const int skc  = tid & 3;               // k-chunk 0..3
    // rows >= M read adjacent ws regions: valid memory, never stored (guarded)
    const size_t arow = (size_t)(bm + srow) * K;

    f32x4 acc[2][2 * HB] = {};

    for (int k0 = 0; k0 < K; k0 += 32) {
        short8v a0 = *(const short8v*)&Ahi[arow + k0 + skc * 8];
        short8v l0 = *(const short8v*)&Alo[arow + k0 + skc * 8];
        short8v bh_s[HB], bl_s[HB];
        #pragma unroll
        for (int r = 0; r < HB; ++r) {
            size_t brow = (size_t)(bn + r * 64 + srow) * K;
            bh_s[r] = *(const short8v*)&Bhi[brow + k0 + skc * 8];
            bl_s[r] = *(const short8v*)&Blo[brow + k0 + skc * 8];
        }
        __syncthreads();                 // previous iteration's reads done
        *(short8v*)(As_hi + skc * 1024 + srow * 16) = a0;
        *(short8v*)(As_lo + skc * 1024 + srow * 16) = l0;
        #pragma unroll
        for (int r = 0; r < HB; ++r) {
            *(short8v*)(Bs_hi + skc * BCH + (r * 64 + srow) * 16) = bh_s[r];
            *(short8v*)(Bs_lo + skc * BCH + (r * 64 + srow) * 16) = bl_s[r];
        }
        __syncthreads();

        short8v ah[2], al[2];
        #pragma unroll
        for (int mi = 0; mi < 2; ++mi) {
            int row = wm * 32 + mi * 16 + r15;
            ah[mi] = *(const short8v*)(As_hi + g4 * 1024 + row * 16);
            al[mi] = *(const short8v*)(As_lo + g4 * 1024 + row * 16);
        }
        #pragma unroll
        for (int nj = 0; nj < 2 * HB; ++nj) {
            int row = wn * (HB * 32) + nj * 16 + r15;
            short8v bh = *(const short8v*)(Bs_hi + g4 * BCH + row * 16);
            short8v bl = *(const short8v*)(Bs_lo + g4 * BCH + row * 16);
            #pragma unroll
            for (int mi = 0; mi < 2; ++mi) {
                acc[mi][nj] = __builtin_amdgcn_mfma_f32_16x16x32_bf16(ah[mi], bh, acc[mi][nj], 0, 0, 0);
                acc[mi][nj] = __builtin_amdgcn_mfma_f32_16x16x32_bf16(ah[mi], bl, acc[mi][nj], 0, 0, 0);
                acc[mi][nj] = __builtin_amdgcn_mfma_f32_16x16x32_bf16(al[mi], bh, acc[mi][nj], 0, 0, 0);
            }
        }
    }
    __syncthreads();                    // all waves done reading staging LDS

    // ---- epilogue: h2 transpose + fused per-head scores ----
    ushort_t* h2 = (ushort_t*)smem;     // [64 rows][HB*64 cols] fp16, col XOR-swizzle
    const int headbase = (bn >> 6) + wn * HW;
    float asv[2 * HB], adv[2 * HB];
    #pragma unroll
    for (int nj = 0; nj < 2 * HB; ++nj) {
        int hg = headbase + (nj >> 2);
        asv[nj] = a_src[hg * 64 + (nj & 3) * 16 + r15];
        adv[nj] = a_dst[hg * 64 + (nj & 3) * 16 + r15];
    }
    #pragma unroll
    for (int mi = 0; mi < 2; ++mi) {
        #pragma unroll
        for (int reg = 0; reg < 4; ++reg) {
            int row_l = wm * 32 + mi * 16 + g4 * 4 + reg;     // 0..63
            int csw = ((row_l >> 2) & 3) << 2;
            #pragma unroll
            for (int hh = 0; hh < HW; ++hh) {
                float pS = 0.f, pD = 0.f;
                #pragma unroll
                for (int njg = 0; njg < 4; ++njg) {
                    int nj = hh * 4 + njg;
                    float v = acc[mi][nj][reg];
                    int col_l = wn * (HB * 32) + nj * 16 + r15;
                    h2[row_l * (HB * 64) + (col_l ^ csw)] = f2h_bits(v);
                    pS += v * asv[nj];
                    pD += v * adv[nj];
                }
                #pragma unroll
                for (int off = 1; off < 16; off <<= 1) {  // reduce over 16 r15 lanes
                    pS += __shfl_xor(pS, off);
                    pD += __shfl_xor(pD, off);
                }
                if (r15 == 0) {          // single writer per (row_l, head)
                    sSs[row_l][wn * HW + hh] = pS;
                    sDs[row_l][wn * HW + hh] = pD;
                }
            }
        }
    }
    __syncthreads();

    // h16 plane writes: HB/2 planes; per node 64 uint (=256B) contiguous
    uint_t* upout = (uint_t*)h16;
    const size_t psz = (size_t)NNODES * 64;
    for (int u = tid; u < 64 * 64 * HW; u += 256) {
        int pp = u >> 12;
        int rem = u & 4095;
        int n_l = rem >> 6, c = rem & 63;
        if (bm + n_l < M) {
            int csw = ((n_l >> 2) & 3) << 2;
            uint_t lo = h2[n_l * (HB * 64) + pp * 128 + (c ^ csw)];
            uint_t hi = h2[n_l * (HB * 64) + pp * 128 + 64 + (c ^ csw)];
            upout[(size_t)((bn >> 7) + pp) * psz + (size_t)(bm + n_l) * 64 + c] =
                lo | (hi << 16);
        }
    }
    // scores out + per-head block max
    for (int idx = tid; idx < 64 * HB; idx += 256) {
        int row = idx / HB, hl = idx - row * HB;
        if (bm + row < M) {
            int hg = (bn >> 6) + hl;
            float vS = sSs[row][hl];
            ssrc[(size_t)(bm + row) * H + hg] = vS;
            sdst[(size_t)(bm + row) * H + hg] = sDs[row][hl];
            atomicMax(&gblk[hl], fmap(vS));
        }
    }
    __syncthreads();
    if (tid < HB) atomicMax(&gmaxu[(bn >> 6) + tid], gblk[tid]);
}

// ============================ CSR build =====================================
__global__ void deg_kernel(const int* __restrict__ ei, int E, int Nn,
                           int* __restrict__ deg) {
    int e = blockIdx.x * blockDim.x + threadIdx.x;
    int tot = E + Nn;
    if (e >= tot) return;
    int d = (e < E) ? ei[E + e] : (e - E);
    atomicAdd(&deg[d], 1);
}

// two-level scan: (1) per-block local inclusive scan, (2) 1-wave scan of block
// sums, (3) add carries + derive cursor
__global__ __launch_bounds__(1024)
void scan1_kernel(const int* __restrict__ deg, int* __restrict__ offs,
                  int* __restrict__ bsum, int n) {
    __shared__ int sh[1024];
    int t = threadIdx.x;
    int i = blockIdx.x * 1024 + t;
    int v = (i < n) ? deg[i] : 0;
    sh[t] = v;
    __syncthreads();
    for (int off = 1; off < 1024; off <<= 1) {
        int add = (t >= off) ? sh[t - off] : 0;
        __syncthreads();
        sh[t] += add;
        __syncthreads();
    }
    if (i < n) offs[i + 1] = sh[t];
    if (t == 1023) bsum[blockIdx.x] = sh[1023];
}

__global__ __launch_bounds__(64)
void scan2_kernel(const int* __restrict__ bsum, int* __restrict__ bexcl, int nb) {
    int t = threadIdx.x;
    int v = (t < nb) ? bsum[t] : 0;
    int orig = v;
    #pragma unroll
    for (int off = 1; off < 64; off <<= 1) {
        int u = __shfl_up(v, off);
        if (t >= off) v += u;
    }
    if (t < nb) bexcl[t] = v - orig;
}

__global__ void scan3_kernel(const int* __restrict__ deg, int* __restrict__ offs,
                             const int* __restrict__ bexcl, int* __restrict__ cursor,
                             int n) {
    int i = blockIdx.x * blockDim.x + threadIdx.x;
    if (i == 0) offs[0] = 0;
    if (i < n) {
        int inc = offs[i + 1] + bexcl[i >> 10];
        offs[i + 1] = inc;
        cursor[i] = inc - deg[i];
    }
}

__global__ void scatter_kernel(const int* __restrict__ ei, int E, int Nn,
                               int* __restrict__ cursor, int* __restrict__ csr_src) {
    int e = blockIdx.x * blockDim.x + threadIdx.x;
    int tot = E + Nn;
    if (e >= tot) return;
    int s, d;
    if (e < E) { s = ei[e]; d = ei[E + e]; }
    else       { s = d = e - E; }
    int pos = atomicAdd(&cursor[d], 1);
    csr_src[pos] = s;
}

// ---------------- vector load of ssrc row [H floats] ----------------
template<int H>
__device__ inline void loadS(const float* __restrict__ p, float* v) {
    if constexpr (H == 4) {
        float4 t = *(const float4*)p;
        v[0] = t.x; v[1] = t.y; v[2] = t.z; v[3] = t.w;
    } else {
        const float2* q = (const float2*)p;
        float2 a = q[0], b = q[1], c = q[2];
        v[0] = a.x; v[1] = a.y; v[2] = b.x; v[3] = b.y; v[4] = c.x; v[5] = c.y;
    }
}

// ====== fused aggregation: smw folded in via per-chunk lane=edge phase ======
// wave per node. Per 64-edge chunk:
//   phase 1 (lane = edge): gather ssrc[csr[...]], compute the H weights ONCE
//     per edge (global-max shift), keep in registers, accumulate partial den.
//   phase 2 (lane = channel): U-unrolled fp16 plane gathers with
//     w = __shfl(wreg, j), s = __shfl(sreg, j) register broadcasts.
template<int H, bool MEAN>
__global__ __launch_bounds__(256)
void agg_kernel(const ushort_t* __restrict__ h16, const float* __restrict__ ssrc,
                const float* __restrict__ sdst, const uint_t* __restrict__ gmaxu,
                const int* __restrict__ offs, const int* __restrict__ csr,
                const float* __restrict__ bias, float* __restrict__ outf,
                ushort_t* __restrict__ ohi, ushort_t* __restrict__ olo, int Nn) {
    constexpr int P = H / 2;
    constexpr int U = (H == 4) ? 8 : 4;
    int wid = (blockIdx.x * blockDim.x + threadIdx.x) >> 6;
    int lane = threadIdx.x & 63;
    if (wid >= Nn) return;
    int beg = offs[wid], end = offs[wid + 1];
    const uint_t* up = (const uint_t*)h16;
    const size_t psz = (size_t)Nn * 64;

    float sd[H], mx[H], den[H];
    #pragma unroll
    for (int h = 0; h < H; ++h) {
        sd[h] = sdst[wid * H + h];
        float t = funmap(gmaxu[h]) + sd[h];
        mx[h] = t > 0.f ? t : 0.2f * t;     // leaky monotone: >= all edge scores
        den[h] = 0.f;
    }

    float acc0[H] = {}, acc1[H] = {};
    for (int cbeg = beg; cbeg < end; cbeg += 64) {
        int cdeg = end - cbeg; if (cdeg > 64) cdeg = 64;
        // ---- phase 1: lane = edge ----
        float wreg[H];
        int sreg = 0;
        #pragma unroll
        for (int h = 0; h < H; ++h) wreg[h] = 0.f;
        if (lane < cdeg) {
            sreg = csr[cbeg + lane];
            float sv[H];
            loadS<H>(ssrc + (size_t)sreg * H, sv);
            #pragma unroll
            for (int h = 0; h < H; ++h) {
                float sc = sv[h] + sd[h];
                sc = sc > 0.f ? sc : 0.2f * sc;
                float w = __expf(sc - mx[h]);
                wreg[h] = w;
                den[h] += w;
            }
        }
        // ---- phase 2: lane = channel ----
        int i = 0;
        for (; i + U <= cdeg; i += U) {
            int s[U];
            #pragma unroll
            for (int j = 0; j < U; ++j) s[j] = __shfl(sreg, i + j);
            uint_t g[U][P];
            #pragma unroll
            for (int j = 0; j < U; ++j)
                #pragma unroll
                for (int p = 0; p < P; ++p)
                    g[j][p] = up[(size_t)p * psz + (size_t)s[j] * 64 + lane];
            float w[U][H];
            #pragma unroll
            for (int j = 0; j < U; ++j)
                #pragma unroll
                for (int h = 0; h < H; ++h) w[j][h] = __shfl(wreg[h], i + j);
            #pragma unroll
            for (int j = 0; j < U; ++j) {
                float v[H];
                #pragma unroll
                for (int p = 0; p < P; ++p) cvt2(g[j][p], v[2 * p], v[2 * p + 1]);
                float* a = (j & 1) ? acc1 : acc0;
                #pragma unroll
                for (int h = 0; h < H; ++h) a[h] += w[j][h] * v[h];
            }
        }
        for (; i < cdeg; ++i) {
            int s = __shfl(sreg, i);
            float v[H];
            #pragma unroll
            for (int p = 0; p < P; ++p) {
                uint_t g = up[(size_t)p * psz + (size_t)s * 64 + lane];
                cvt2(g, v[2 * p], v[2 * p + 1]);
            }
            #pragma unroll
            for (int h = 0; h < H; ++h) acc0[h] += __shfl(wreg[h], i) * v[h];
        }
    }

    // reduce den across lanes (same order as old smw)
    #pragma unroll
    for (int h = 0; h < H; ++h) {
        #pragma unroll
        for (int off = 32; off; off >>= 1) den[h] += __shfl_xor(den[h], off);
    }

    if (!MEAN) {
        #pragma unroll
        for (int h = 0; h < H; ++h) {
            float val = (acc0[h] + acc1[h]) / (den[h] + 1e-16f) + bias[h * 64 + lane];
            val = val > 0.f ? val : expm1f(val);   // ELU
            size_t idx = (size_t)wid * (H * 64) + h * 64 + lane;
            ushort_t hb = f2bf_bits(val);
            ohi[idx] = hb;
            olo[idx] = f2bf_bits(val - bfbits2f(hb));
        }
    } else {
        float m = 0.f;
        #pragma unroll
        for (int h = 0; h < H; ++h)
            m += (acc0[h] + acc1[h]) / (den[h] + 1e-16f);
        outf[(size_t)wid * 64 + lane] = m * (1.f / (float)H) + bias[lane];
    }
}

// ============================ launch ========================================
extern "C" void kernel_launch(void* const* d_in, const int* in_sizes, int n_in,
                              void* d_out, int out_size, void* d_ws, size_t ws_size,
                              hipStream_t stream) {
    const float* x     = (const float*)d_in[0];
    const int*   ei    = (const int*)d_in[1];
    const float* W1    = (const float*)d_in[2];
    const float* a1s   = (const float*)d_in[3];
    const float* a1d   = (const float*)d_in[4];
    const float* b1    = (const float*)d_in[5];
    const float* W2    = (const float*)d_in[6];
    const float* a2s   = (const float*)d_in[7];
    const float* a2d   = (const float*)d_in[8];
    const float* b2    = (const float*)d_in[9];
    const float* W3    = (const float*)d_in[10];
    const float* a3s   = (const float*)d_in[11];
    const float* a3d   = (const float*)d_in[12];
    const float* b3    = (const float*)d_in[13];
    float* out = (float*)d_out;

    const int Nn = NNODES;
    const int E  = in_sizes[1] / 2;
    const int Etot = E + Nn;

    char* p = (char*)d_ws;
    auto carve = [&](size_t bytes) {
        char* r = p;
        p += (bytes + 255) & ~(size_t)255;
        return (void*)r;
    };
    ushort_t* h16   = (ushort_t*)carve((size_t)Nn * 384 * 2);   // up to 3 planes
    ushort_t* R1    = (ushort_t*)carve((size_t)Nn * 256 * 4);
    ushort_t* x_hi  = R1;
    ushort_t* x_lo  = R1 + (size_t)Nn * 128;
    ushort_t* x1_hi = R1;
    ushort_t* x1_lo = R1 + (size_t)Nn * 256;
    ushort_t* w1hi  = (ushort_t*)carve((size_t)128 * 256 * 2);
    ushort_t* w1lo  = (ushort_t*)carve((size_t)128 * 256 * 2);
    ushort_t* w2hi  = (ushort_t*)carve((size_t)256 * 256 * 2);
    ushort_t* w2lo  = (ushort_t*)carve((size_t)256 * 256 * 2);
    ushort_t* w3hi  = (ushort_t*)carve((size_t)256 * 384 * 2);
    ushort_t* w3lo  = (ushort_t*)carve((size_t)256 * 384 * 2);
    float* ssrc   = (float*)carve((size_t)Nn * 6 * 4);
    float* sdst   = (float*)carve((size_t)Nn * 6 * 4);
    int*   deg    = (int*)carve((size_t)Nn * 4);
    int*   offs   = (int*)carve((size_t)(Nn + 1) * 4);
    int*   cursor = (int*)carve((size_t)Nn * 4);
    int*   csr    = (int*)carve((size_t)Etot * 4);
    uint_t* gmaxu = (uint_t*)carve(18 * 4);
    int*   bsum   = (int*)carve(64 * 4);
    int*   bexcl  = (int*)carve(64 * 4);

    // -------- CSR build --------
    hipMemsetAsync(deg, 0, (size_t)Nn * 4, stream);
    hipMemsetAsync(gmaxu, 0, 18 * 4, stream);   // 0 == fmap(-inf) lower bound
    {
        int nb = (Etot + 255) / 256;
        int nsb = (Nn + 1023) / 1024;
        deg_kernel<<<nb, 256, 0, stream>>>(ei, E, Nn, deg);
        scan1_kernel<<<nsb, 1024, 0, stream>>>(deg, offs, bsum, Nn);
        scan2_kernel<<<1, 64, 0, stream>>>(bsum, bexcl, nsb);
        scan3_kernel<<<(Nn + 255) / 256, 256, 0, stream>>>(deg, offs, bexcl, cursor, Nn);
        scatter_kernel<<<nb, 256, 0, stream>>>(ei, E, Nn, cursor, csr);
    }

    // -------- weight + input prep --------
    {
        int n4 = Nn * 128 / 4;
        split_kernel<<<(n4 + 255) / 256, 256, 0, stream>>>(
            (const float4*)x, (ushort4*)x_hi, (ushort4*)x_lo, n4);
        int wtot = 128 * 256 + 256 * 256 + 256 * 384;
        wprep_all<<<(wtot + 255) / 256, 256, 0, stream>>>(W1, W2, W3, w1hi, w1lo,
                                                          w2hi, w2lo, w3hi, w3lo);
    }

    const int node_blocks = (Nn + 3) / 4;
    const int gemm_rows = (Nn + 63) / 64;

    // -------- layer 1: [50000,128] @ [128,256], H=4, concat+ELU --------
    {
        dim3 g(2, gemm_rows);   // HB=2 -> NC=2 (A panel small: 25.6 MB)
        gemm_fused<4, 2><<<g, 256, 0, stream>>>(x_hi, x_lo, w1hi, w1lo, h16,
                                                ssrc, sdst, gmaxu + 0, a1s, a1d,
                                                Nn, 128);
        agg_kernel<4, false><<<node_blocks, 256, 0, stream>>>(h16, ssrc, sdst, gmaxu + 0,
                                                              offs, csr, b1,
                                                              nullptr, x1_hi, x1_lo, Nn);
    }
    // -------- layer 2: [50000,256] @ [256,256], H=4, concat+ELU --------
    {
        dim3 g(1, gemm_rows);   // HB=4 -> NC=1: A fetched once
        gemm_fused<4, 4><<<g, 256, 0, stream>>>(x1_hi, x1_lo, w2hi, w2lo, h16,
                                                ssrc, sdst, gmaxu + 6, a2s, a2d,
                                                Nn, 256);
        agg_kernel<4, false><<<node_blocks, 256, 0, stream>>>(h16, ssrc, sdst, gmaxu + 6,
                                                              offs, csr, b2,
                                                              nullptr, x1_hi, x1_lo, Nn);
    }
    // -------- layer 3: [50000,256] @ [256,384], H=6, mean --------
    {
        dim3 g(1, gemm_rows);   // HB=6 -> NC=1: A fetched once
        gemm_fused<6, 6><<<g, 256, 0, stream>>>(x1_hi, x1_lo, w3hi, w3lo, h16,
                                                ssrc, sdst, gmaxu + 12, a3s, a3d,
                                                Nn, 256);
        agg_kernel<6, true><<<node_blocks, 256, 0, stream>>>(h16, ssrc, sdst, gmaxu + 12,
                                                             offs, csr, b3,
                                                             out, nullptr, nullptr, Nn);
    }
}

// Round 14
// 551.742 us; speedup vs baseline: 1.1042x; 1.1042x over previous
//
#include <hip/hip_runtime.h>
#include <hip/hip_bf16.h>
#include <hip/hip_fp16.h>
#include <math.h>

#define NNODES 50000

typedef __attribute__((ext_vector_type(8))) short short8v;
typedef __attribute__((ext_vector_type(4))) float f32x4;
typedef unsigned short ushort_t;
typedef unsigned int uint_t;

// ---------------- bf16 / fp16 helpers ----------------
__device__ inline ushort_t f2bf_bits(float v) {
    union { __hip_bfloat16 b; ushort_t u; } c;
    c.b = __float2bfloat16(v);
    return c.u;
}
__device__ inline float bfbits2f(ushort_t u) {
    union { __hip_bfloat16 b; ushort_t u; } c;
    c.u = u;
    return __bfloat162float(c.b);
}
__device__ inline ushort_t f2h_bits(float v) {
    union { __half h; ushort_t u; } c;
    c.h = __float2half(v);
    return c.u;
}
__device__ inline void cvt2(uint_t u, float& a, float& b) {
    union { uint_t u; __half2 h; } c; c.u = u;
    a = __low2float(c.h); b = __high2float(c.h);
}
// monotone float<->uint mapping (for atomicMax on floats incl. negatives)
__device__ inline uint_t fmap(float f) {
    uint_t b = __float_as_uint(f);
    return (b & 0x80000000u) ? ~b : (b | 0x80000000u);
}
__device__ inline float funmap(uint_t u) {
    return __uint_as_float((u & 0x80000000u) ? (u & 0x7FFFFFFFu) : ~u);
}

// split fp32 -> (hi, lo) bf16 pair, vectorized x4
__global__ __launch_bounds__(256)
void split_kernel(const float4* __restrict__ in, ushort4* __restrict__ hi,
                  ushort4* __restrict__ lo, int n4) {
    int i = blockIdx.x * blockDim.x + threadIdx.x;
    if (i >= n4) return;
    float4 v = in[i];
    ushort4 h, l;
    h.x = f2bf_bits(v.x); l.x = f2bf_bits(v.x - bfbits2f(h.x));
    h.y = f2bf_bits(v.y); l.y = f2bf_bits(v.y - bfbits2f(h.y));
    h.z = f2bf_bits(v.z); l.z = f2bf_bits(v.z - bfbits2f(h.z));
    h.w = f2bf_bits(v.w); l.w = f2bf_bits(v.w - bfbits2f(h.w));
    hi[i] = h; lo[i] = l;
}

// all three weight transposes/splits in one launch
__global__ __launch_bounds__(256)
void wprep_all(const float* __restrict__ W1, const float* __restrict__ W2,
               const float* __restrict__ W3,
               ushort_t* __restrict__ w1h, ushort_t* __restrict__ w1l,
               ushort_t* __restrict__ w2h, ushort_t* __restrict__ w2l,
               ushort_t* __restrict__ w3h, ushort_t* __restrict__ w3l) {
    int idx = blockIdx.x * blockDim.x + threadIdx.x;
    const float* W; ushort_t* hT; ushort_t* lT; int K, N;
    if (idx < 128 * 256) { W = W1; hT = w1h; lT = w1l; K = 128; N = 256; }
    else if (idx < 128 * 256 + 256 * 256) {
        idx -= 128 * 256; W = W2; hT = w2h; lT = w2l; K = 256; N = 256;
    } else {
        idx -= 128 * 256 + 256 * 256;
        if (idx >= 256 * 384) return;
        W = W3; hT = w3h; lT = w3l; K = 256; N = 384;
    }
    int k = idx / N, n = idx - k * N;
    float v = W[idx];
    ushort_t hb = f2bf_bits(v);
    hT[(size_t)n * K + k] = hb;
    lT[(size_t)n * K + k] = f2bf_bits(v - bfbits2f(hb));
}

// ============ fused split-bf16 3-pass MFMA GEMM + pack + score ==============
// C = A[M][K] * B[K][N] (B stored transposed [N][K], hi/lo bf16).
// BM=64, BN=HB*64 (HB heads per block), BK=32; 4 waves (2x2), wave tile
// 32 x (HB*32). HB=2 (24KB LDS, 6 blk/CU) proven for l1/l3; HB=4 (43KB LDS,
// 3 blk/CU) gives NC=1 for layer 2 (A panel fetched once).
// LDS staging k-chunk-major: conflict-free ds_read_b128 fragments.
// Epilogue: acc -> LDS fp16 (XOR-swizzled) -> HB/2 head-pair planes
// h16[p][n][c][2], fused per-head s_src/s_dst dot-reduce, per-head global max.
template<int H, int HB>
__global__ __launch_bounds__(256)
void gemm_fused(const ushort_t* __restrict__ Ahi, const ushort_t* __restrict__ Alo,
                const ushort_t* __restrict__ Bhi, const ushort_t* __restrict__ Blo,
                ushort_t* __restrict__ h16, float* __restrict__ ssrc,
                float* __restrict__ sdst, uint_t* __restrict__ gmaxu,
                const float* __restrict__ a_src, const float* __restrict__ a_dst,
                int M, int K) {
    constexpr int BCH = HB * 1024;          // B LDS k-chunk stride (HB*64 rows x 16B)
    constexpr int SMEMB = 8192 + 2 * HB * 4096;   // A(8KB) + B hi/lo
    constexpr int HW = HB / 2;              // heads per wave
    __shared__ char smem[SMEMB];            // staging / epilogue h2 union
    __shared__ float sSs[64][HB], sDs[64][HB];
    __shared__ uint_t gblk[8];

    const int tid = threadIdx.x;
    const int lane = tid & 63;
    const int wid = tid >> 6;
    const int wm = wid >> 1, wn = wid & 1;
    const int bm = blockIdx.y * 64;
    const int bn = blockIdx.x * (HB * 64);
    const int r15 = lane & 15;
    const int g4 = lane >> 4;

    if (tid < HB) gblk[tid] = 0;

    char* As_hi = smem;                     // 4 chunks x 64 rows x 16B = 4KB
    char* As_lo = smem + 4096;
    char* Bs_hi = smem + 8192;              // 4 chunks x HB*64 rows x 16B
    char* Bs_lo = smem + 8192 + HB * 4096;

    const int srow = tid >> 2;              // 0..63
    const int skc  = tid & 3;               // k-chunk 0..3
    // rows >= M read adjacent ws regions: valid memory, never stored (guarded)
    const size_t arow = (size_t)(bm + srow) * K;

    f32x4 acc[2][2 * HB] = {};

    for (int k0 = 0; k0 < K; k0 += 32) {
        short8v a0 = *(const short8v*)&Ahi[arow + k0 + skc * 8];
        short8v l0 = *(const short8v*)&Alo[arow + k0 + skc * 8];
        short8v bh_s[HB], bl_s[HB];
        #pragma unroll
        for (int r = 0; r < HB; ++r) {
            size_t brow = (size_t)(bn + r * 64 + srow) * K;
            bh_s[r] = *(const short8v*)&Bhi[brow + k0 + skc * 8];
            bl_s[r] = *(const short8v*)&Blo[brow + k0 + skc * 8];
        }
        __syncthreads();                 // previous iteration's reads done
        *(short8v*)(As_hi + skc * 1024 + srow * 16) = a0;
        *(short8v*)(As_lo + skc * 1024 + srow * 16) = l0;
        #pragma unroll
        for (int r = 0; r < HB; ++r) {
            *(short8v*)(Bs_hi + skc * BCH + (r * 64 + srow) * 16) = bh_s[r];
            *(short8v*)(Bs_lo + skc * BCH + (r * 64 + srow) * 16) = bl_s[r];
        }
        __syncthreads();

        short8v ah[2], al[2];
        #pragma unroll
        for (int mi = 0; mi < 2; ++mi) {
            int row = wm * 32 + mi * 16 + r15;
            ah[mi] = *(const short8v*)(As_hi + g4 * 1024 + row * 16);
            al[mi] = *(const short8v*)(As_lo + g4 * 1024 + row * 16);
        }
        #pragma unroll
        for (int nj = 0; nj < 2 * HB; ++nj) {
            int row = wn * (HB * 32) + nj * 16 + r15;
            short8v bh = *(const short8v*)(Bs_hi + g4 * BCH + row * 16);
            short8v bl = *(const short8v*)(Bs_lo + g4 * BCH + row * 16);
            #pragma unroll
            for (int mi = 0; mi < 2; ++mi) {
                acc[mi][nj] = __builtin_amdgcn_mfma_f32_16x16x32_bf16(ah[mi], bh, acc[mi][nj], 0, 0, 0);
                acc[mi][nj] = __builtin_amdgcn_mfma_f32_16x16x32_bf16(ah[mi], bl, acc[mi][nj], 0, 0, 0);
                acc[mi][nj] = __builtin_amdgcn_mfma_f32_16x16x32_bf16(al[mi], bh, acc[mi][nj], 0, 0, 0);
            }
        }
    }
    __syncthreads();                    // all waves done reading staging LDS

    // ---- epilogue: h2 transpose + fused per-head scores ----
    ushort_t* h2 = (ushort_t*)smem;     // [64 rows][HB*64 cols] fp16, col XOR-swizzle
    const int headbase = (bn >> 6) + wn * HW;
    float asv[2 * HB], adv[2 * HB];
    #pragma unroll
    for (int nj = 0; nj < 2 * HB; ++nj) {
        int hg = headbase + (nj >> 2);
        asv[nj] = a_src[hg * 64 + (nj & 3) * 16 + r15];
        adv[nj] = a_dst[hg * 64 + (nj & 3) * 16 + r15];
    }
    #pragma unroll
    for (int mi = 0; mi < 2; ++mi) {
        #pragma unroll
        for (int reg = 0; reg < 4; ++reg) {
            int row_l = wm * 32 + mi * 16 + g4 * 4 + reg;     // 0..63
            int csw = ((row_l >> 2) & 3) << 2;
            #pragma unroll
            for (int hh = 0; hh < HW; ++hh) {
                float pS = 0.f, pD = 0.f;
                #pragma unroll
                for (int njg = 0; njg < 4; ++njg) {
                    int nj = hh * 4 + njg;
                    float v = acc[mi][nj][reg];
                    int col_l = wn * (HB * 32) + nj * 16 + r15;
                    h2[row_l * (HB * 64) + (col_l ^ csw)] = f2h_bits(v);
                    pS += v * asv[nj];
                    pD += v * adv[nj];
                }
                #pragma unroll
                for (int off = 1; off < 16; off <<= 1) {  // reduce over 16 r15 lanes
                    pS += __shfl_xor(pS, off);
                    pD += __shfl_xor(pD, off);
                }
                if (r15 == 0) {          // single writer per (row_l, head)
                    sSs[row_l][wn * HW + hh] = pS;
                    sDs[row_l][wn * HW + hh] = pD;
                }
            }
        }
    }
    __syncthreads();

    // h16 plane writes: HB/2 planes; per node 64 uint (=256B) contiguous
    uint_t* upout = (uint_t*)h16;
    const size_t psz = (size_t)NNODES * 64;
    for (int u = tid; u < 64 * 64 * HW; u += 256) {
        int pp = u >> 12;
        int rem = u & 4095;
        int n_l = rem >> 6, c = rem & 63;
        if (bm + n_l < M) {
            int csw = ((n_l >> 2) & 3) << 2;
            uint_t lo = h2[n_l * (HB * 64) + pp * 128 + (c ^ csw)];
            uint_t hi = h2[n_l * (HB * 64) + pp * 128 + 64 + (c ^ csw)];
            upout[(size_t)((bn >> 7) + pp) * psz + (size_t)(bm + n_l) * 64 + c] =
                lo | (hi << 16);
        }
    }
    // scores out + per-head block max
    for (int idx = tid; idx < 64 * HB; idx += 256) {
        int row = idx / HB, hl = idx - row * HB;
        if (bm + row < M) {
            int hg = (bn >> 6) + hl;
            float vS = sSs[row][hl];
            ssrc[(size_t)(bm + row) * H + hg] = vS;
            sdst[(size_t)(bm + row) * H + hg] = sDs[row][hl];
            atomicMax(&gblk[hl], fmap(vS));
        }
    }
    __syncthreads();
    if (tid < HB) atomicMax(&gmaxu[(bn >> 6) + tid], gblk[tid]);
}

// ============================ CSR build =====================================
__global__ void deg_kernel(const int* __restrict__ ei, int E, int Nn,
                           int* __restrict__ deg) {
    int e = blockIdx.x * blockDim.x + threadIdx.x;
    int tot = E + Nn;
    if (e >= tot) return;
    int d = (e < E) ? ei[E + e] : (e - E);
    atomicAdd(&deg[d], 1);
}

// two-level scan: (1) per-block local inclusive scan, (2) 1-wave scan of block
// sums, (3) add carries + derive cursor
__global__ __launch_bounds__(1024)
void scan1_kernel(const int* __restrict__ deg, int* __restrict__ offs,
                  int* __restrict__ bsum, int n) {
    __shared__ int sh[1024];
    int t = threadIdx.x;
    int i = blockIdx.x * 1024 + t;
    int v = (i < n) ? deg[i] : 0;
    sh[t] = v;
    __syncthreads();
    for (int off = 1; off < 1024; off <<= 1) {
        int add = (t >= off) ? sh[t - off] : 0;
        __syncthreads();
        sh[t] += add;
        __syncthreads();
    }
    if (i < n) offs[i + 1] = sh[t];
    if (t == 1023) bsum[blockIdx.x] = sh[1023];
}

__global__ __launch_bounds__(64)
void scan2_kernel(const int* __restrict__ bsum, int* __restrict__ bexcl, int nb) {
    int t = threadIdx.x;
    int v = (t < nb) ? bsum[t] : 0;
    int orig = v;
    #pragma unroll
    for (int off = 1; off < 64; off <<= 1) {
        int u = __shfl_up(v, off);
        if (t >= off) v += u;
    }
    if (t < nb) bexcl[t] = v - orig;
}

__global__ void scan3_kernel(const int* __restrict__ deg, int* __restrict__ offs,
                             const int* __restrict__ bexcl, int* __restrict__ cursor,
                             int n) {
    int i = blockIdx.x * blockDim.x + threadIdx.x;
    if (i == 0) offs[0] = 0;
    if (i < n) {
        int inc = offs[i + 1] + bexcl[i >> 10];
        offs[i + 1] = inc;
        cursor[i] = inc - deg[i];
    }
}

__global__ void scatter_kernel(const int* __restrict__ ei, int E, int Nn,
                               int* __restrict__ cursor, int* __restrict__ csr_src) {
    int e = blockIdx.x * blockDim.x + threadIdx.x;
    int tot = E + Nn;
    if (e >= tot) return;
    int s, d;
    if (e < E) { s = ei[e]; d = ei[E + e]; }
    else       { s = d = e - E; }
    int pos = atomicAdd(&cursor[d], 1);
    csr_src[pos] = s;
}

// ---------------- vector load of ssrc row [H floats] ----------------
template<int H>
__device__ inline void loadS(const float* __restrict__ p, float* v) {
    if constexpr (H == 4) {
        float4 t = *(const float4*)p;
        v[0] = t.x; v[1] = t.y; v[2] = t.z; v[3] = t.w;
    } else {
        const float2* q = (const float2*)p;
        float2 a = q[0], b = q[1], c = q[2];
        v[0] = a.x; v[1] = a.y; v[2] = b.x; v[3] = b.y; v[4] = c.x; v[5] = c.y;
    }
}

// ====== fused aggregation: smw folded in via per-chunk lane=edge phase ======
// wave per node. Per 64-edge chunk:
//   phase 1 (lane = edge): gather ssrc[csr[...]], compute the H weights ONCE
//     per edge (global-max shift), keep in registers, accumulate partial den.
//   phase 2 (lane = channel): U-unrolled fp16 plane gathers with
//     w = __shfl(wreg, j), s = __shfl(sreg, j) register broadcasts.
template<int H, bool MEAN>
__global__ __launch_bounds__(256)
void agg_kernel(const ushort_t* __restrict__ h16, const float* __restrict__ ssrc,
                const float* __restrict__ sdst, const uint_t* __restrict__ gmaxu,
                const int* __restrict__ offs, const int* __restrict__ csr,
                const float* __restrict__ bias, float* __restrict__ outf,
                ushort_t* __restrict__ ohi, ushort_t* __restrict__ olo, int Nn) {
    constexpr int P = H / 2;
    constexpr int U = (H == 4) ? 8 : 4;
    int wid = (blockIdx.x * blockDim.x + threadIdx.x) >> 6;
    int lane = threadIdx.x & 63;
    if (wid >= Nn) return;
    int beg = offs[wid], end = offs[wid + 1];
    const uint_t* up = (const uint_t*)h16;
    const size_t psz = (size_t)Nn * 64;

    float sd[H], mx[H], den[H];
    #pragma unroll
    for (int h = 0; h < H; ++h) {
        sd[h] = sdst[wid * H + h];
        float t = funmap(gmaxu[h]) + sd[h];
        mx[h] = t > 0.f ? t : 0.2f * t;     // leaky monotone: >= all edge scores
        den[h] = 0.f;
    }

    float acc0[H] = {}, acc1[H] = {};
    for (int cbeg = beg; cbeg < end; cbeg += 64) {
        int cdeg = end - cbeg; if (cdeg > 64) cdeg = 64;
        // ---- phase 1: lane = edge ----
        float wreg[H];
        int sreg = 0;
        #pragma unroll
        for (int h = 0; h < H; ++h) wreg[h] = 0.f;
        if (lane < cdeg) {
            sreg = csr[cbeg + lane];
            float sv[H];
            loadS<H>(ssrc + (size_t)sreg * H, sv);
            #pragma unroll
            for (int h = 0; h < H; ++h) {
                float sc = sv[h] + sd[h];
                sc = sc > 0.f ? sc : 0.2f * sc;
                float w = __expf(sc - mx[h]);
                wreg[h] = w;
                den[h] += w;
            }
        }
        // ---- phase 2: lane = channel ----
        int i = 0;
        for (; i + U <= cdeg; i += U) {
            int s[U];
            #pragma unroll
            for (int j = 0; j < U; ++j) s[j] = __shfl(sreg, i + j);
            uint_t g[U][P];
            #pragma unroll
            for (int j = 0; j < U; ++j)
                #pragma unroll
                for (int p = 0; p < P; ++p)
                    g[j][p] = up[(size_t)p * psz + (size_t)s[j] * 64 + lane];
            float w[U][H];
            #pragma unroll
            for (int j = 0; j < U; ++j)
                #pragma unroll
                for (int h = 0; h < H; ++h) w[j][h] = __shfl(wreg[h], i + j);
            #pragma unroll
            for (int j = 0; j < U; ++j) {
                float v[H];
                #pragma unroll
                for (int p = 0; p < P; ++p) cvt2(g[j][p], v[2 * p], v[2 * p + 1]);
                float* a = (j & 1) ? acc1 : acc0;
                #pragma unroll
                for (int h = 0; h < H; ++h) a[h] += w[j][h] * v[h];
            }
        }
        for (; i < cdeg; ++i) {
            int s = __shfl(sreg, i);
            float v[H];
            #pragma unroll
            for (int p = 0; p < P; ++p) {
                uint_t g = up[(size_t)p * psz + (size_t)s * 64 + lane];
                cvt2(g, v[2 * p], v[2 * p + 1]);
            }
            #pragma unroll
            for (int h = 0; h < H; ++h) acc0[h] += __shfl(wreg[h], i) * v[h];
        }
    }

    // reduce den across lanes (same order as old smw)
    #pragma unroll
    for (int h = 0; h < H; ++h) {
        #pragma unroll
        for (int off = 32; off; off >>= 1) den[h] += __shfl_xor(den[h], off);
    }

    if (!MEAN) {
        #pragma unroll
        for (int h = 0; h < H; ++h) {
            float val = (acc0[h] + acc1[h]) / (den[h] + 1e-16f) + bias[h * 64 + lane];
            val = val > 0.f ? val : expm1f(val);   // ELU
            size_t idx = (size_t)wid * (H * 64) + h * 64 + lane;
            ushort_t hb = f2bf_bits(val);
            ohi[idx] = hb;
            olo[idx] = f2bf_bits(val - bfbits2f(hb));
        }
    } else {
        float m = 0.f;
        #pragma unroll
        for (int h = 0; h < H; ++h)
            m += (acc0[h] + acc1[h]) / (den[h] + 1e-16f);
        outf[(size_t)wid * 64 + lane] = m * (1.f / (float)H) + bias[lane];
    }
}

// ============================ launch ========================================
extern "C" void kernel_launch(void* const* d_in, const int* in_sizes, int n_in,
                              void* d_out, int out_size, void* d_ws, size_t ws_size,
                              hipStream_t stream) {
    const float* x     = (const float*)d_in[0];
    const int*   ei    = (const int*)d_in[1];
    const float* W1    = (const float*)d_in[2];
    const float* a1s   = (const float*)d_in[3];
    const float* a1d   = (const float*)d_in[4];
    const float* b1    = (const float*)d_in[5];
    const float* W2    = (const float*)d_in[6];
    const float* a2s   = (const float*)d_in[7];
    const float* a2d   = (const float*)d_in[8];
    const float* b2    = (const float*)d_in[9];
    const float* W3    = (const float*)d_in[10];
    const float* a3s   = (const float*)d_in[11];
    const float* a3d   = (const float*)d_in[12];
    const float* b3    = (const float*)d_in[13];
    float* out = (float*)d_out;

    const int Nn = NNODES;
    const int E  = in_sizes[1] / 2;
    const int Etot = E + Nn;

    char* p = (char*)d_ws;
    auto carve = [&](size_t bytes) {
        char* r = p;
        p += (bytes + 255) & ~(size_t)255;
        return (void*)r;
    };
    ushort_t* h16   = (ushort_t*)carve((size_t)Nn * 384 * 2);   // up to 3 planes
    ushort_t* R1    = (ushort_t*)carve((size_t)Nn * 256 * 4);
    ushort_t* x_hi  = R1;
    ushort_t* x_lo  = R1 + (size_t)Nn * 128;
    ushort_t* x1_hi = R1;
    ushort_t* x1_lo = R1 + (size_t)Nn * 256;
    ushort_t* w1hi  = (ushort_t*)carve((size_t)128 * 256 * 2);
    ushort_t* w1lo  = (ushort_t*)carve((size_t)128 * 256 * 2);
    ushort_t* w2hi  = (ushort_t*)carve((size_t)256 * 256 * 2);
    ushort_t* w2lo  = (ushort_t*)carve((size_t)256 * 256 * 2);
    ushort_t* w3hi  = (ushort_t*)carve((size_t)256 * 384 * 2);
    ushort_t* w3lo  = (ushort_t*)carve((size_t)256 * 384 * 2);
    float* ssrc   = (float*)carve((size_t)Nn * 6 * 4);
    float* sdst   = (float*)carve((size_t)Nn * 6 * 4);
    int*   deg    = (int*)carve((size_t)Nn * 4);
    int*   offs   = (int*)carve((size_t)(Nn + 1) * 4);
    int*   cursor = (int*)carve((size_t)Nn * 4);
    int*   csr    = (int*)carve((size_t)Etot * 4);
    uint_t* gmaxu = (uint_t*)carve(18 * 4);
    int*   bsum   = (int*)carve(64 * 4);
    int*   bexcl  = (int*)carve(64 * 4);

    // -------- CSR build --------
    hipMemsetAsync(deg, 0, (size_t)Nn * 4, stream);
    hipMemsetAsync(gmaxu, 0, 18 * 4, stream);   // 0 == fmap(-inf) lower bound
    {
        int nb = (Etot + 255) / 256;
        int nsb = (Nn + 1023) / 1024;
        deg_kernel<<<nb, 256, 0, stream>>>(ei, E, Nn, deg);
        scan1_kernel<<<nsb, 1024, 0, stream>>>(deg, offs, bsum, Nn);
        scan2_kernel<<<1, 64, 0, stream>>>(bsum, bexcl, nsb);
        scan3_kernel<<<(Nn + 255) / 256, 256, 0, stream>>>(deg, offs, bexcl, cursor, Nn);
        scatter_kernel<<<nb, 256, 0, stream>>>(ei, E, Nn, cursor, csr);
    }

    // -------- weight + input prep --------
    {
        int n4 = Nn * 128 / 4;
        split_kernel<<<(n4 + 255) / 256, 256, 0, stream>>>(
            (const float4*)x, (ushort4*)x_hi, (ushort4*)x_lo, n4);
        int wtot = 128 * 256 + 256 * 256 + 256 * 384;
        wprep_all<<<(wtot + 255) / 256, 256, 0, stream>>>(W1, W2, W3, w1hi, w1lo,
                                                          w2hi, w2lo, w3hi, w3lo);
    }

    const int node_blocks = (Nn + 3) / 4;
    const int gemm_rows = (Nn + 63) / 64;

    // -------- layer 1: [50000,128] @ [128,256], H=4, concat+ELU --------
    {
        dim3 g(2, gemm_rows);   // HB=2, NC=2 (A panel 25.6 MB, cheap)
        gemm_fused<4, 2><<<g, 256, 0, stream>>>(x_hi, x_lo, w1hi, w1lo, h16,
                                                ssrc, sdst, gmaxu + 0, a1s, a1d,
                                                Nn, 128);
        agg_kernel<4, false><<<node_blocks, 256, 0, stream>>>(h16, ssrc, sdst, gmaxu + 0,
                                                              offs, csr, b1,
                                                              nullptr, x1_hi, x1_lo, Nn);
    }
    // -------- layer 2: [50000,256] @ [256,256], H=4, concat+ELU --------
    {
        dim3 g(1, gemm_rows);   // HB=4 -> NC=1: A fetched once; 43KB LDS, 3 blk/CU
        gemm_fused<4, 4><<<g, 256, 0, stream>>>(x1_hi, x1_lo, w2hi, w2lo, h16,
                                                ssrc, sdst, gmaxu + 6, a2s, a2d,
                                                Nn, 256);
        agg_kernel<4, false><<<node_blocks, 256, 0, stream>>>(h16, ssrc, sdst, gmaxu + 6,
                                                              offs, csr, b2,
                                                              nullptr, x1_hi, x1_lo, Nn);
    }
    // -------- layer 3: [50000,256] @ [256,384], H=6, mean --------
    {
        dim3 g(3, gemm_rows);   // HB=2, NC=3 (proven shape; avoids R13 LDS cliff)
        gemm_fused<6, 2><<<g, 256, 0, stream>>>(x1_hi, x1_lo, w3hi, w3lo, h16,
                                                ssrc, sdst, gmaxu + 12, a3s, a3d,
                                                Nn, 256);
        agg_kernel<6, true><<<node_blocks, 256, 0, stream>>>(h16, ssrc, sdst, gmaxu + 12,
                                                             offs, csr, b3,
                                                             out, nullptr, nullptr, Nn);
    }
}

// Round 15
// 543.478 us; speedup vs baseline: 1.1210x; 1.0152x over previous
//
#include <hip/hip_runtime.h>
#include <hip/hip_bf16.h>
#include <hip/hip_fp16.h>
#include <math.h>

#define NNODES 50000

typedef __attribute__((ext_vector_type(8))) short short8v;
typedef __attribute__((ext_vector_type(4))) float f32x4;
typedef unsigned short ushort_t;
typedef unsigned int uint_t;

// ---------------- bf16 / fp16 helpers ----------------
__device__ inline ushort_t f2bf_bits(float v) {
    union { __hip_bfloat16 b; ushort_t u; } c;
    c.b = __float2bfloat16(v);
    return c.u;
}
__device__ inline float bfbits2f(ushort_t u) {
    union { __hip_bfloat16 b; ushort_t u; } c;
    c.u = u;
    return __bfloat162float(c.b);
}
__device__ inline ushort_t f2h_bits(float v) {
    union { __half h; ushort_t u; } c;
    c.h = __float2half(v);
    return c.u;
}
__device__ inline void cvt2(uint_t u, float& a, float& b) {
    union { uint_t u; __half2 h; } c; c.u = u;
    a = __low2float(c.h); b = __high2float(c.h);
}
// monotone float<->uint mapping (for atomicMax on floats incl. negatives)
__device__ inline uint_t fmap(float f) {
    uint_t b = __float_as_uint(f);
    return (b & 0x80000000u) ? ~b : (b | 0x80000000u);
}
__device__ inline float funmap(uint_t u) {
    return __uint_as_float((u & 0x80000000u) ? (u & 0x7FFFFFFFu) : ~u);
}

// split fp32 -> (hi, lo) bf16 pair, vectorized x4
__global__ __launch_bounds__(256)
void split_kernel(const float4* __restrict__ in, ushort4* __restrict__ hi,
                  ushort4* __restrict__ lo, int n4) {
    int i = blockIdx.x * blockDim.x + threadIdx.x;
    if (i >= n4) return;
    float4 v = in[i];
    ushort4 h, l;
    h.x = f2bf_bits(v.x); l.x = f2bf_bits(v.x - bfbits2f(h.x));
    h.y = f2bf_bits(v.y); l.y = f2bf_bits(v.y - bfbits2f(h.y));
    h.z = f2bf_bits(v.z); l.z = f2bf_bits(v.z - bfbits2f(h.z));
    h.w = f2bf_bits(v.w); l.w = f2bf_bits(v.w - bfbits2f(h.w));
    hi[i] = h; lo[i] = l;
}

// all three weight transposes/splits in one launch
__global__ __launch_bounds__(256)
void wprep_all(const float* __restrict__ W1, const float* __restrict__ W2,
               const float* __restrict__ W3,
               ushort_t* __restrict__ w1h, ushort_t* __restrict__ w1l,
               ushort_t* __restrict__ w2h, ushort_t* __restrict__ w2l,
               ushort_t* __restrict__ w3h, ushort_t* __restrict__ w3l) {
    int idx = blockIdx.x * blockDim.x + threadIdx.x;
    const float* W; ushort_t* hT; ushort_t* lT; int K, N;
    if (idx < 128 * 256) { W = W1; hT = w1h; lT = w1l; K = 128; N = 256; }
    else if (idx < 128 * 256 + 256 * 256) {
        idx -= 128 * 256; W = W2; hT = w2h; lT = w2l; K = 256; N = 256;
    } else {
        idx -= 128 * 256 + 256 * 256;
        if (idx >= 256 * 384) return;
        W = W3; hT = w3h; lT = w3l; K = 256; N = 384;
    }
    int k = idx / N, n = idx - k * N;
    float v = W[idx];
    ushort_t hb = f2bf_bits(v);
    hT[(size_t)n * K + k] = hb;
    lT[(size_t)n * K + k] = f2bf_bits(v - bfbits2f(hb));
}

// ============ fused split-bf16 3-pass MFMA GEMM + pack + score ==============
// C = A[M][K] * B[K][N] (B stored transposed [N][K], hi/lo bf16).
// BM=64, BN=HB*64 (HB heads per block), BK=32; 4 waves (2x2), wave tile
// 32 x (HB*32). HB=2 (24KB LDS, ~6 blk/CU) is the measured-best shape.
// LDS staging k-chunk-major: conflict-free ds_read_b128 fragments.
// Epilogue: acc -> LDS fp16 (XOR-swizzled) -> HB/2 head-pair planes
// h16[p][n][c][2], fused per-head s_src/s_dst dot-reduce, per-head global max.
template<int H, int HB>
__global__ __launch_bounds__(256)
void gemm_fused(const ushort_t* __restrict__ Ahi, const ushort_t* __restrict__ Alo,
                const ushort_t* __restrict__ Bhi, const ushort_t* __restrict__ Blo,
                ushort_t* __restrict__ h16, float* __restrict__ ssrc,
                float* __restrict__ sdst, uint_t* __restrict__ gmaxu,
                const float* __restrict__ a_src, const float* __restrict__ a_dst,
                int M, int K) {
    constexpr int BCH = HB * 1024;          // B LDS k-chunk stride (HB*64 rows x 16B)
    constexpr int SMEMB = 8192 + 2 * HB * 4096;   // A(8KB) + B hi/lo
    constexpr int HW = HB / 2;              // heads per wave
    __shared__ char smem[SMEMB];            // staging / epilogue h2 union
    __shared__ float sSs[64][HB], sDs[64][HB];
    __shared__ uint_t gblk[8];

    const int tid = threadIdx.x;
    const int lane = tid & 63;
    const int wid = tid >> 6;
    const int wm = wid >> 1, wn = wid & 1;
    const int bm = blockIdx.y * 64;
    const int bn = blockIdx.x * (HB * 64);
    const int r15 = lane & 15;
    const int g4 = lane >> 4;

    if (tid < HB) gblk[tid] = 0;

    char* As_hi = smem;                     // 4 chunks x 64 rows x 16B = 4KB
    char* As_lo = smem + 4096;
    char* Bs_hi = smem + 8192;              // 4 chunks x HB*64 rows x 16B
    char* Bs_lo = smem + 8192 + HB * 4096;

    const int srow = tid >> 2;              // 0..63
    const int skc  = tid & 3;               // k-chunk 0..3
    // rows >= M read adjacent ws regions: valid memory, never stored (guarded)
    const size_t arow = (size_t)(bm + srow) * K;

    f32x4 acc[2][2 * HB] = {};

    for (int k0 = 0; k0 < K; k0 += 32) {
        short8v a0 = *(const short8v*)&Ahi[arow + k0 + skc * 8];
        short8v l0 = *(const short8v*)&Alo[arow + k0 + skc * 8];
        short8v bh_s[HB], bl_s[HB];
        #pragma unroll
        for (int r = 0; r < HB; ++r) {
            size_t brow = (size_t)(bn + r * 64 + srow) * K;
            bh_s[r] = *(const short8v*)&Bhi[brow + k0 + skc * 8];
            bl_s[r] = *(const short8v*)&Blo[brow + k0 + skc * 8];
        }
        __syncthreads();                 // previous iteration's reads done
        *(short8v*)(As_hi + skc * 1024 + srow * 16) = a0;
        *(short8v*)(As_lo + skc * 1024 + srow * 16) = l0;
        #pragma unroll
        for (int r = 0; r < HB; ++r) {
            *(short8v*)(Bs_hi + skc * BCH + (r * 64 + srow) * 16) = bh_s[r];
            *(short8v*)(Bs_lo + skc * BCH + (r * 64 + srow) * 16) = bl_s[r];
        }
        __syncthreads();

        short8v ah[2], al[2];
        #pragma unroll
        for (int mi = 0; mi < 2; ++mi) {
            int row = wm * 32 + mi * 16 + r15;
            ah[mi] = *(const short8v*)(As_hi + g4 * 1024 + row * 16);
            al[mi] = *(const short8v*)(As_lo + g4 * 1024 + row * 16);
        }
        #pragma unroll
        for (int nj = 0; nj < 2 * HB; ++nj) {
            int row = wn * (HB * 32) + nj * 16 + r15;
            short8v bh = *(const short8v*)(Bs_hi + g4 * BCH + row * 16);
            short8v bl = *(const short8v*)(Bs_lo + g4 * BCH + row * 16);
            #pragma unroll
            for (int mi = 0; mi < 2; ++mi) {
                acc[mi][nj] = __builtin_amdgcn_mfma_f32_16x16x32_bf16(ah[mi], bh, acc[mi][nj], 0, 0, 0);
                acc[mi][nj] = __builtin_amdgcn_mfma_f32_16x16x32_bf16(ah[mi], bl, acc[mi][nj], 0, 0, 0);
                acc[mi][nj] = __builtin_amdgcn_mfma_f32_16x16x32_bf16(al[mi], bh, acc[mi][nj], 0, 0, 0);
            }
        }
    }
    __syncthreads();                    // all waves done reading staging LDS

    // ---- epilogue: h2 transpose + fused per-head scores ----
    ushort_t* h2 = (ushort_t*)smem;     // [64 rows][HB*64 cols] fp16, col XOR-swizzle
    const int headbase = (bn >> 6) + wn * HW;
    float asv[2 * HB], adv[2 * HB];
    #pragma unroll
    for (int nj = 0; nj < 2 * HB; ++nj) {
        int hg = headbase + (nj >> 2);
        asv[nj] = a_src[hg * 64 + (nj & 3) * 16 + r15];
        adv[nj] = a_dst[hg * 64 + (nj & 3) * 16 + r15];
    }
    #pragma unroll
    for (int mi = 0; mi < 2; ++mi) {
        #pragma unroll
        for (int reg = 0; reg < 4; ++reg) {
            int row_l = wm * 32 + mi * 16 + g4 * 4 + reg;     // 0..63
            int csw = ((row_l >> 2) & 3) << 2;
            #pragma unroll
            for (int hh = 0; hh < HW; ++hh) {
                float pS = 0.f, pD = 0.f;
                #pragma unroll
                for (int njg = 0; njg < 4; ++njg) {
                    int nj = hh * 4 + njg;
                    float v = acc[mi][nj][reg];
                    int col_l = wn * (HB * 32) + nj * 16 + r15;
                    h2[row_l * (HB * 64) + (col_l ^ csw)] = f2h_bits(v);
                    pS += v * asv[nj];
                    pD += v * adv[nj];
                }
                #pragma unroll
                for (int off = 1; off < 16; off <<= 1) {  // reduce over 16 r15 lanes
                    pS += __shfl_xor(pS, off);
                    pD += __shfl_xor(pD, off);
                }
                if (r15 == 0) {          // single writer per (row_l, head)
                    sSs[row_l][wn * HW + hh] = pS;
                    sDs[row_l][wn * HW + hh] = pD;
                }
            }
        }
    }
    __syncthreads();

    // h16 plane writes: HB/2 planes; per node 64 uint (=256B) contiguous
    uint_t* upout = (uint_t*)h16;
    const size_t psz = (size_t)NNODES * 64;
    for (int u = tid; u < 64 * 64 * HW; u += 256) {
        int pp = u >> 12;
        int rem = u & 4095;
        int n_l = rem >> 6, c = rem & 63;
        if (bm + n_l < M) {
            int csw = ((n_l >> 2) & 3) << 2;
            uint_t lo = h2[n_l * (HB * 64) + pp * 128 + (c ^ csw)];
            uint_t hi = h2[n_l * (HB * 64) + pp * 128 + 64 + (c ^ csw)];
            upout[(size_t)((bn >> 7) + pp) * psz + (size_t)(bm + n_l) * 64 + c] =
                lo | (hi << 16);
        }
    }
    // scores out + per-head block max
    for (int idx = tid; idx < 64 * HB; idx += 256) {
        int row = idx / HB, hl = idx - row * HB;
        if (bm + row < M) {
            int hg = (bn >> 6) + hl;
            float vS = sSs[row][hl];
            ssrc[(size_t)(bm + row) * H + hg] = vS;
            sdst[(size_t)(bm + row) * H + hg] = sDs[row][hl];
            atomicMax(&gblk[hl], fmap(vS));
        }
    }
    __syncthreads();
    if (tid < HB) atomicMax(&gmaxu[(bn >> 6) + tid], gblk[tid]);
}

// ============================ CSR build =====================================
__global__ void deg_kernel(const int* __restrict__ ei, int E, int Nn,
                           int* __restrict__ deg) {
    int e = blockIdx.x * blockDim.x + threadIdx.x;
    int tot = E + Nn;
    if (e >= tot) return;
    int d = (e < E) ? ei[E + e] : (e - E);
    atomicAdd(&deg[d], 1);
}

// two-level scan: (1) per-block local inclusive scan, (2) 1-wave scan of block
// sums, (3) add carries + derive cursor
__global__ __launch_bounds__(1024)
void scan1_kernel(const int* __restrict__ deg, int* __restrict__ offs,
                  int* __restrict__ bsum, int n) {
    __shared__ int sh[1024];
    int t = threadIdx.x;
    int i = blockIdx.x * 1024 + t;
    int v = (i < n) ? deg[i] : 0;
    sh[t] = v;
    __syncthreads();
    for (int off = 1; off < 1024; off <<= 1) {
        int add = (t >= off) ? sh[t - off] : 0;
        __syncthreads();
        sh[t] += add;
        __syncthreads();
    }
    if (i < n) offs[i + 1] = sh[t];
    if (t == 1023) bsum[blockIdx.x] = sh[1023];
}

__global__ __launch_bounds__(64)
void scan2_kernel(const int* __restrict__ bsum, int* __restrict__ bexcl, int nb) {
    int t = threadIdx.x;
    int v = (t < nb) ? bsum[t] : 0;
    int orig = v;
    #pragma unroll
    for (int off = 1; off < 64; off <<= 1) {
        int u = __shfl_up(v, off);
        if (t >= off) v += u;
    }
    if (t < nb) bexcl[t] = v - orig;
}

__global__ void scan3_kernel(const int* __restrict__ deg, int* __restrict__ offs,
                             const int* __restrict__ bexcl, int* __restrict__ cursor,
                             int n) {
    int i = blockIdx.x * blockDim.x + threadIdx.x;
    if (i == 0) offs[0] = 0;
    if (i < n) {
        int inc = offs[i + 1] + bexcl[i >> 10];
        offs[i + 1] = inc;
        cursor[i] = inc - deg[i];
    }
}

__global__ void scatter_kernel(const int* __restrict__ ei, int E, int Nn,
                               int* __restrict__ cursor, int* __restrict__ csr_src) {
    int e = blockIdx.x * blockDim.x + threadIdx.x;
    int tot = E + Nn;
    if (e >= tot) return;
    int s, d;
    if (e < E) { s = ei[e]; d = ei[E + e]; }
    else       { s = d = e - E; }
    int pos = atomicAdd(&cursor[d], 1);
    csr_src[pos] = s;
}

// ---------------- vector load of ssrc row [H floats] ----------------
template<int H>
__device__ inline void loadS(const float* __restrict__ p, float* v) {
    if constexpr (H == 4) {
        float4 t = *(const float4*)p;
        v[0] = t.x; v[1] = t.y; v[2] = t.z; v[3] = t.w;
    } else {
        const float2* q = (const float2*)p;
        float2 a = q[0], b = q[1], c = q[2];
        v[0] = a.x; v[1] = a.y; v[2] = b.x; v[3] = b.y; v[4] = c.x; v[5] = c.y;
    }
}

// ====== fused aggregation: smw folded in via per-chunk lane=edge phase ======
// wave per node. Per 64-edge chunk:
//   phase 1 (lane = edge): gather ssrc[csr[...]], compute the H weights ONCE
//     per edge (global-max shift), keep in registers, accumulate partial den.
//   phase 2 (lane = channel): U-unrolled fp16 plane gathers with
//     w = __shfl(wreg, j), s = __shfl(sreg, j) register broadcasts.
template<int H, bool MEAN>
__global__ __launch_bounds__(256)
void agg_kernel(const ushort_t* __restrict__ h16, const float* __restrict__ ssrc,
                const float* __restrict__ sdst, const uint_t* __restrict__ gmaxu,
                const int* __restrict__ offs, const int* __restrict__ csr,
                const float* __restrict__ bias, float* __restrict__ outf,
                ushort_t* __restrict__ ohi, ushort_t* __restrict__ olo, int Nn) {
    constexpr int P = H / 2;
    constexpr int U = (H == 4) ? 8 : 4;
    int wid = (blockIdx.x * blockDim.x + threadIdx.x) >> 6;
    int lane = threadIdx.x & 63;
    if (wid >= Nn) return;
    int beg = offs[wid], end = offs[wid + 1];
    const uint_t* up = (const uint_t*)h16;
    const size_t psz = (size_t)Nn * 64;

    float sd[H], mx[H], den[H];
    #pragma unroll
    for (int h = 0; h < H; ++h) {
        sd[h] = sdst[wid * H + h];
        float t = funmap(gmaxu[h]) + sd[h];
        mx[h] = t > 0.f ? t : 0.2f * t;     // leaky monotone: >= all edge scores
        den[h] = 0.f;
    }

    float acc0[H] = {}, acc1[H] = {};
    for (int cbeg = beg; cbeg < end; cbeg += 64) {
        int cdeg = end - cbeg; if (cdeg > 64) cdeg = 64;
        // ---- phase 1: lane = edge ----
        float wreg[H];
        int sreg = 0;
        #pragma unroll
        for (int h = 0; h < H; ++h) wreg[h] = 0.f;
        if (lane < cdeg) {
            sreg = csr[cbeg + lane];
            float sv[H];
            loadS<H>(ssrc + (size_t)sreg * H, sv);
            #pragma unroll
            for (int h = 0; h < H; ++h) {
                float sc = sv[h] + sd[h];
                sc = sc > 0.f ? sc : 0.2f * sc;
                float w = __expf(sc - mx[h]);
                wreg[h] = w;
                den[h] += w;
            }
        }
        // ---- phase 2: lane = channel ----
        int i = 0;
        for (; i + U <= cdeg; i += U) {
            int s[U];
            #pragma unroll
            for (int j = 0; j < U; ++j) s[j] = __shfl(sreg, i + j);
            uint_t g[U][P];
            #pragma unroll
            for (int j = 0; j < U; ++j)
                #pragma unroll
                for (int p = 0; p < P; ++p)
                    g[j][p] = up[(size_t)p * psz + (size_t)s[j] * 64 + lane];
            float w[U][H];
            #pragma unroll
            for (int j = 0; j < U; ++j)
                #pragma unroll
                for (int h = 0; h < H; ++h) w[j][h] = __shfl(wreg[h], i + j);
            #pragma unroll
            for (int j = 0; j < U; ++j) {
                float v[H];
                #pragma unroll
                for (int p = 0; p < P; ++p) cvt2(g[j][p], v[2 * p], v[2 * p + 1]);
                float* a = (j & 1) ? acc1 : acc0;
                #pragma unroll
                for (int h = 0; h < H; ++h) a[h] += w[j][h] * v[h];
            }
        }
        for (; i < cdeg; ++i) {
            int s = __shfl(sreg, i);
            float v[H];
            #pragma unroll
            for (int p = 0; p < P; ++p) {
                uint_t g = up[(size_t)p * psz + (size_t)s * 64 + lane];
                cvt2(g, v[2 * p], v[2 * p + 1]);
            }
            #pragma unroll
            for (int h = 0; h < H; ++h) acc0[h] += __shfl(wreg[h], i) * v[h];
        }
    }

    // reduce den across lanes (same order as old smw)
    #pragma unroll
    for (int h = 0; h < H; ++h) {
        #pragma unroll
        for (int off = 32; off; off >>= 1) den[h] += __shfl_xor(den[h], off);
    }

    if (!MEAN) {
        #pragma unroll
        for (int h = 0; h < H; ++h) {
            float val = (acc0[h] + acc1[h]) / (den[h] + 1e-16f) + bias[h * 64 + lane];
            val = val > 0.f ? val : expm1f(val);   // ELU
            size_t idx = (size_t)wid * (H * 64) + h * 64 + lane;
            ushort_t hb = f2bf_bits(val);
            ohi[idx] = hb;
            olo[idx] = f2bf_bits(val - bfbits2f(hb));
        }
    } else {
        float m = 0.f;
        #pragma unroll
        for (int h = 0; h < H; ++h)
            m += (acc0[h] + acc1[h]) / (den[h] + 1e-16f);
        outf[(size_t)wid * 64 + lane] = m * (1.f / (float)H) + bias[lane];
    }
}

// ============================ launch ========================================
extern "C" void kernel_launch(void* const* d_in, const int* in_sizes, int n_in,
                              void* d_out, int out_size, void* d_ws, size_t ws_size,
                              hipStream_t stream) {
    const float* x     = (const float*)d_in[0];
    const int*   ei    = (const int*)d_in[1];
    const float* W1    = (const float*)d_in[2];
    const float* a1s   = (const float*)d_in[3];
    const float* a1d   = (const float*)d_in[4];
    const float* b1    = (const float*)d_in[5];
    const float* W2    = (const float*)d_in[6];
    const float* a2s   = (const float*)d_in[7];
    const float* a2d   = (const float*)d_in[8];
    const float* b2    = (const float*)d_in[9];
    const float* W3    = (const float*)d_in[10];
    const float* a3s   = (const float*)d_in[11];
    const float* a3d   = (const float*)d_in[12];
    const float* b3    = (const float*)d_in[13];
    float* out = (float*)d_out;

    const int Nn = NNODES;
    const int E  = in_sizes[1] / 2;
    const int Etot = E + Nn;

    char* p = (char*)d_ws;
    auto carve = [&](size_t bytes) {
        char* r = p;
        p += (bytes + 255) & ~(size_t)255;
        return (void*)r;
    };
    ushort_t* h16   = (ushort_t*)carve((size_t)Nn * 384 * 2);   // up to 3 planes
    ushort_t* R1    = (ushort_t*)carve((size_t)Nn * 256 * 4);
    ushort_t* x_hi  = R1;
    ushort_t* x_lo  = R1 + (size_t)Nn * 128;
    ushort_t* x1_hi = R1;
    ushort_t* x1_lo = R1 + (size_t)Nn * 256;
    ushort_t* w1hi  = (ushort_t*)carve((size_t)128 * 256 * 2);
    ushort_t* w1lo  = (ushort_t*)carve((size_t)128 * 256 * 2);
    ushort_t* w2hi  = (ushort_t*)carve((size_t)256 * 256 * 2);
    ushort_t* w2lo  = (ushort_t*)carve((size_t)256 * 256 * 2);
    ushort_t* w3hi  = (ushort_t*)carve((size_t)256 * 384 * 2);
    ushort_t* w3lo  = (ushort_t*)carve((size_t)256 * 384 * 2);
    float* ssrc   = (float*)carve((size_t)Nn * 6 * 4);
    float* sdst   = (float*)carve((size_t)Nn * 6 * 4);
    int*   deg    = (int*)carve((size_t)Nn * 4);
    int*   offs   = (int*)carve((size_t)(Nn + 1) * 4);
    int*   cursor = (int*)carve((size_t)Nn * 4);
    int*   csr    = (int*)carve((size_t)Etot * 4);
    uint_t* gmaxu = (uint_t*)carve(18 * 4);
    int*   bsum   = (int*)carve(64 * 4);
    int*   bexcl  = (int*)carve(64 * 4);

    // -------- CSR build --------
    hipMemsetAsync(deg, 0, (size_t)Nn * 4, stream);
    hipMemsetAsync(gmaxu, 0, 18 * 4, stream);   // 0 == fmap(-inf) lower bound
    {
        int nb = (Etot + 255) / 256;
        int nsb = (Nn + 1023) / 1024;
        deg_kernel<<<nb, 256, 0, stream>>>(ei, E, Nn, deg);
        scan1_kernel<<<nsb, 1024, 0, stream>>>(deg, offs, bsum, Nn);
        scan2_kernel<<<1, 64, 0, stream>>>(bsum, bexcl, nsb);
        scan3_kernel<<<(Nn + 255) / 256, 256, 0, stream>>>(deg, offs, bexcl, cursor, Nn);
        scatter_kernel<<<nb, 256, 0, stream>>>(ei, E, Nn, cursor, csr);
    }

    // -------- weight + input prep --------
    {
        int n4 = Nn * 128 / 4;
        split_kernel<<<(n4 + 255) / 256, 256, 0, stream>>>(
            (const float4*)x, (ushort4*)x_hi, (ushort4*)x_lo, n4);
        int wtot = 128 * 256 + 256 * 256 + 256 * 384;
        wprep_all<<<(wtot + 255) / 256, 256, 0, stream>>>(W1, W2, W3, w1hi, w1lo,
                                                          w2hi, w2lo, w3hi, w3lo);
    }

    const int node_blocks = (Nn + 3) / 4;
    const int gemm_rows = (Nn + 63) / 64;

    // -------- layer 1: [50000,128] @ [128,256], H=4, concat+ELU --------
    {
        dim3 g(2, gemm_rows);   // HB=2, NC=2
        gemm_fused<4, 2><<<g, 256, 0, stream>>>(x_hi, x_lo, w1hi, w1lo, h16,
                                                ssrc, sdst, gmaxu + 0, a1s, a1d,
                                                Nn, 128);
        agg_kernel<4, false><<<node_blocks, 256, 0, stream>>>(h16, ssrc, sdst, gmaxu + 0,
                                                              offs, csr, b1,
                                                              nullptr, x1_hi, x1_lo, Nn);
    }
    // -------- layer 2: [50000,256] @ [256,256], H=4, concat+ELU --------
    {
        dim3 g(2, gemm_rows);   // HB=2, NC=2 (R12-proven best)
        gemm_fused<4, 2><<<g, 256, 0, stream>>>(x1_hi, x1_lo, w2hi, w2lo, h16,
                                                ssrc, sdst, gmaxu + 6, a2s, a2d,
                                                Nn, 256);
        agg_kernel<4, false><<<node_blocks, 256, 0, stream>>>(h16, ssrc, sdst, gmaxu + 6,
                                                              offs, csr, b2,
                                                              nullptr, x1_hi, x1_lo, Nn);
    }
    // -------- layer 3: [50000,256] @ [256,384], H=6, mean --------
    {
        dim3 g(3, gemm_rows);   // HB=2, NC=3
        gemm_fused<6, 2><<<g, 256, 0, stream>>>(x1_hi, x1_lo, w3hi, w3lo, h16,
                                                ssrc, sdst, gmaxu + 12, a3s, a3d,
                                                Nn, 256);
        agg_kernel<6, true><<<node_blocks, 256, 0, stream>>>(h16, ssrc, sdst, gmaxu + 12,
                                                             offs, csr, b3,
                                                             out, nullptr, nullptr, Nn);
    }
}